// Round 9
// baseline (94.423 us; speedup 1.0000x reference)
//
#include <hip/hip_runtime.h>
#include <hip/hip_bf16.h>
#include <math.h>

#define DDIM 32
#define KMIX 8

typedef short bf16x8 __attribute__((ext_vector_type(8)));
typedef float f32x4 __attribute__((ext_vector_type(4)));

__device__ __forceinline__ ushort to_bf16_rne(float f) {
    unsigned u = __builtin_bit_cast(unsigned, f);
    u = (u + 0x7FFFu + ((u >> 16) & 1u)) >> 16;
    return (ushort)u;
}

// ---------- prep: GJ inverse (SPD, no pivoting) -> Cholesky(Sigma^-1) -> panels.
// (unchanged from round 8)
__global__ __launch_bounds__(512) void gmm_prep(
    const float* __restrict__ S, const float* __restrict__ mus,
    const float* __restrict__ phis, ushort* __restrict__ Wtg,
    ushort* __restrict__ Upan, float* __restrict__ pa2, float* __restrict__ pc)
{
    __shared__ float aug[DDIM][2 * DDIM + 2];  // stride 66
    __shared__ float ch[DDIM][DDIM + 1];       // stride 33
    __shared__ float pivsave[DDIM];
    __shared__ float amuL[DDIM];
    __shared__ float logL[DDIM];
    const int k = blockIdx.x;
    const int t = threadIdx.x;   // 0..511
    const int r = t >> 4;        // 0..31
    const int c4 = t & 15;       // 0..15

    aug[r][c4]      = S[k * 1024 + r * 32 + c4];
    aug[r][c4 + 16] = S[k * 1024 + r * 32 + c4 + 16];
    aug[r][c4 + 32] = (c4 == r) ? 1.f : 0.f;
    aug[r][c4 + 48] = (c4 + 16 == r) ? 1.f : 0.f;
    __syncthreads();

    for (int p = 0; p < DDIM; ++p) {
        const float piv = aug[p][p];
        const float f   = aug[r][p];
        const float pr0 = aug[p][c4];
        const float pr1 = aug[p][c4 + 16];
        const float pr2 = aug[p][c4 + 32];
        const float pr3 = aug[p][c4 + 48];
        __syncthreads();
        const float ip = 1.f / piv;
        if (r == p) {
            aug[r][c4]      = pr0 * ip;
            aug[r][c4 + 16] = pr1 * ip;
            aug[r][c4 + 32] = pr2 * ip;
            aug[r][c4 + 48] = pr3 * ip;
            if (c4 == 0) pivsave[p] = piv;
        } else {
            const float fi = f * ip;
            aug[r][c4]      = fmaf(-fi, pr0, aug[r][c4]);
            aug[r][c4 + 16] = fmaf(-fi, pr1, aug[r][c4 + 16]);
            aug[r][c4 + 32] = fmaf(-fi, pr2, aug[r][c4 + 32]);
            aug[r][c4 + 48] = fmaf(-fi, pr3, aug[r][c4 + 48]);
        }
        __syncthreads();
    }

    if (t < DDIM) {
        float acc = 0.f;
        for (int d = 0; d < DDIM; ++d)
            acc = fmaf(aug[t][32 + d], mus[k * 32 + d], acc);
        amuL[t] = acc;
        logL[t] = logf(fabsf(pivsave[t]));
    }
    ch[r][c4]      = aug[r][32 + c4];
    ch[r][c4 + 16] = aug[r][48 + c4];
    __syncthreads();

    for (int j = 0; j < DDIM; ++j) {
        const float djj = ch[j][j];
        const float cr  = ch[r][j];
        const float cc0 = ch[c4][j];
        const float cc1 = ch[c4 + 16][j];
        __syncthreads();
        const float irs = rsqrtf(djj);
        const float ird = __builtin_amdgcn_rcpf(djj);
        if (c4 == j)                       ch[r][c4]      = (r >= j) ? cr * irs : 0.f;
        else if (r > j && c4 > j)          ch[r][c4]      = fmaf(-cr * ird, cc0, ch[r][c4]);
        if (c4 + 16 == j)                  ch[r][c4 + 16] = (r >= j) ? cr * irs : 0.f;
        else if (r > j && c4 + 16 > j)     ch[r][c4 + 16] = fmaf(-cr * ird, cc1, ch[r][c4 + 16]);
        __syncthreads();
    }

    {
        const int lane0 = (t >> 3) & 63, j0 = t & 7;
        const int d0 = (lane0 >> 4) * 8 + j0;
        const int e0 = lane0 & 15;
        const int e1 = 16 + e0;
        const float f0 = (d0 >= e0) ? ch[d0][e0] : 0.f;
        const float f1 = (d0 >= e1) ? ch[d0][e1] : 0.f;
        Wtg[k * 1024 + t]       = to_bf16_rne(f0);
        Wtg[k * 1024 + 512 + t] = to_bf16_rne(f1);
    }
    if (t < DDIM)
        Upan[k * 32 + t] = to_bf16_rne(phis[k] * 1.4426950408889634f * amuL[t]);
    if (k == 0 && t >= 256) Upan[t] = 0;  // U rows 8..15 = 0
    if (t == 0) {
        float ldet = 0.f, muAmu = 0.f;
        for (int i = 0; i < DDIM; ++i) {
            ldet += logL[i];
            muAmu = fmaf(amuL[i], mus[k * 32 + i], muAmu);
        }
        const float eld = expf(0.5f * (DDIM * 1.8378770664093453f + ldet));
        const float LOG2E = 1.4426950408889634f;
        pa2[k] = -0.5f * phis[k] * LOG2E;
        pc[k]  = (-0.5f * phis[k] * muAmu - phis[k] * eld) * LOG2E;
    }
}

// ---------- DPP helpers -----------------------------------------------------
template <int CTRL>
__device__ __forceinline__ float dpp_add(float v) {
    int t = __builtin_amdgcn_update_dpp(0, __builtin_bit_cast(int, v), CTRL, 0xF, 0xF, true);
    return v + __builtin_bit_cast(float, t);
}
__device__ __forceinline__ float sel4(float a0, float a1, float a2, float a3, int r) {
    float b0 = (r & 1) ? a1 : a0;
    float b1 = (r & 1) ? a3 : a2;
    return (r & 2) ? b1 : b0;
}
__device__ __forceinline__ float bperm_f(int addr, float v) {
    return __builtin_bit_cast(float, __builtin_amdgcn_ds_bpermute(addr, __builtin_bit_cast(int, v)));
}

// ---------- main (identical body to round 8, templated on tiles-per-wave) ---
// MEASUREMENT ROUND: launched twice (TPWV=5 then TPWV=10, both idempotent,
// same correct output) so main's solo duration = T9 - T8.
template <int TPWV>
__global__ __launch_bounds__(256, 6) void gmm_main(
    const float* __restrict__ X, const ushort* __restrict__ Wtg,
    const ushort* __restrict__ Upan, const float* __restrict__ pa2g,
    const float* __restrict__ pcg, float* __restrict__ out, int N)
{
    __shared__ ushort wtab[KMIX * 1024];  // 16 KiB: [k][h][lane][8 bf16]
    const int tid = threadIdx.x;
    const int lane = tid & 63;
    const int wid = tid >> 6;
    const int g = lane >> 4;
    const int c = lane & 15;
    const int rsel = c & 3;
    const int r1 = g * 4 + rsel;       // output row within tile
    const int p = c >> 2;              // output k-pair (k = 2p, 2p+1)

    {
        const float4* src = (const float4*)Wtg;
        float4* dst = (float4*)wtab;
#pragma unroll
        for (int i = 0; i < 4; ++i) dst[tid + 256 * i] = src[tid + 256 * i];
    }

    const bf16x8 uf = *(const bf16x8*)(Upan + c * 32 + g * 8);  // A-frag of U
    float pcv0 = pcg[0], pcv1 = pcg[1], pcv2 = pcg[2], pcv3 = pcg[3];
    float pcv4 = pcg[4], pcv5 = pcg[5], pcv6 = pcg[6], pcv7 = pcg[7];
    const float m8 = fmaxf(fmaxf(fmaxf(pcv0, pcv1), fmaxf(pcv2, pcv3)),
                           fmaxf(fmaxf(pcv4, pcv5), fmaxf(pcv6, pcv7)));
    const float paA = pa2g[2 * p], paB = pa2g[2 * p + 1];
    const float pcsA = pcg[2 * p] - m8, pcsB = pcg[2 * p + 1] - m8;
    const int src_byte = (((p >> 1) * 16 + r1) << 2);

    const int ntiles = N >> 4;
    const int tile0 = (blockIdx.x * 4 + wid) * TPWV;
    const float* lp = X + (size_t)tile0 * 512 + c * 32 + g * 8;
    float* op = out + (size_t)(tile0 * 16 + r1) * 8 + p * 2;

    const f32x4 zro = {0.f, 0.f, 0.f, 0.f};
    float4 a0 = {0,0,0,0}, a1 = {0,0,0,0};
    if (tile0 < ntiles) { a0 = *(const float4*)lp; a1 = *(const float4*)(lp + 4); }

    __syncthreads();  // wtab ready

#pragma unroll
    for (int it = 0; it < TPWV; ++it) {
        const int tile = tile0 + it;
        float4 b0 = a0, b1 = a1;
        if (it + 1 < TPWV && tile + 1 < ntiles) {
            b0 = *(const float4*)(lp + 512);
            b1 = *(const float4*)(lp + 516);
        }
        if (tile < ntiles) {
            int4 xi;
            xi.x = __builtin_amdgcn_perm(__builtin_bit_cast(unsigned, a0.y), __builtin_bit_cast(unsigned, a0.x), 0x07060302u);
            xi.y = __builtin_amdgcn_perm(__builtin_bit_cast(unsigned, a0.w), __builtin_bit_cast(unsigned, a0.z), 0x07060302u);
            xi.z = __builtin_amdgcn_perm(__builtin_bit_cast(unsigned, a1.y), __builtin_bit_cast(unsigned, a1.x), 0x07060302u);
            xi.w = __builtin_amdgcn_perm(__builtin_bit_cast(unsigned, a1.w), __builtin_bit_cast(unsigned, a1.z), 0x07060302u);
            const bf16x8 xf = __builtin_bit_cast(bf16x8, xi);

            const f32x4 lin = __builtin_amdgcn_mfma_f32_16x16x32_bf16(uf, xf, zro, 0, 0, 0);

            int la = lane * 16;
            asm volatile("" : "+v"(la));
            const char* wb = (const char*)wtab + la;

            float qa = 0.f, qb = 0.f;
#pragma unroll
            for (int k = 0; k < KMIX; ++k) {
                const bf16x8 wf0k = *(const bf16x8*)(wb + (k * 2 + 0) * 1024);
                bf16x8 wf1k = {0, 0, 0, 0, 0, 0, 0, 0};
                if (lane >= 32)  // L lower-tri: rows d<16 of cols e>=16 are zero
                    wf1k = *(const bf16x8*)(wb + (k * 2 + 1) * 1024);
                f32x4 acc0 = __builtin_amdgcn_mfma_f32_16x16x32_bf16(xf, wf0k, zro, 0, 0, 0);
                f32x4 acc1 = __builtin_amdgcn_mfma_f32_16x16x32_bf16(xf, wf1k, zro, 0, 0, 0);
                float p0 = fmaf(acc1[0], acc1[0], acc0[0] * acc0[0]);
                float p1 = fmaf(acc1[1], acc1[1], acc0[1] * acc0[1]);
                float p2 = fmaf(acc1[2], acc1[2], acc0[2] * acc0[2]);
                float p3 = fmaf(acc1[3], acc1[3], acc0[3] * acc0[3]);
                p0 = dpp_add<0xB1>(p0); p0 = dpp_add<0x4E>(p0);
                p1 = dpp_add<0xB1>(p1); p1 = dpp_add<0x4E>(p1);
                p2 = dpp_add<0xB1>(p2); p2 = dpp_add<0x4E>(p2);
                p3 = dpp_add<0xB1>(p3); p3 = dpp_add<0x4E>(p3);
                float v = sel4(p0, p1, p2, p3, rsel);   // keep row g*4+(c&3)
                v = dpp_add<0x124>(v);                  // row_ror:4
                v = dpp_add<0x128>(v);                  // row_ror:8
                if ((k >> 1) == 0) { if (p == 0) { if (k & 1) qb = v; else qa = v; } }
                if ((k >> 1) == 1) { if (p == 1) { if (k & 1) qb = v; else qa = v; } }
                if ((k >> 1) == 2) { if (p == 2) { if (k & 1) qb = v; else qa = v; } }
                if ((k >> 1) == 3) { if (p == 3) { if (k & 1) qb = v; else qa = v; } }
            }

            const float l0 = bperm_f(src_byte, lin[0]);
            const float l1 = bperm_f(src_byte, lin[1]);
            const float l2 = bperm_f(src_byte, lin[2]);
            const float l3 = bperm_f(src_byte, lin[3]);
            const float lina = (p & 1) ? l2 : l0;
            const float linb = (p & 1) ? l3 : l1;
            const float aka = fmaf(paA, qa, pcsA) + lina;
            const float akb = fmaf(paB, qb, pcsB) + linb;

            const float ea = __builtin_amdgcn_exp2f(aka);
            const float eb = __builtin_amdgcn_exp2f(akb);
            float s = ea + eb;
            s = dpp_add<0x124>(s); s = dpp_add<0x128>(s);
            const float inv = __builtin_amdgcn_rcpf(s);
            *(float2*)op = make_float2(ea * inv, eb * inv);
        }
        a0 = b0; a1 = b1;
        lp += 512;
        op += 128;
    }
}

extern "C" void kernel_launch(void* const* d_in, const int* in_sizes, int n_in,
                              void* d_out, int out_size, void* d_ws, size_t ws_size,
                              hipStream_t stream) {
    const float* X    = (const float*)d_in[0];
    const float* mus  = (const float*)d_in[1];
    const float* sig  = (const float*)d_in[2];
    const float* phis = (const float*)d_in[3];
    float* out = (float*)d_out;

    float* ws    = (float*)d_ws;
    float* pa2   = ws;                   // 8 f32
    float* pc    = ws + 8;               // 8 f32
    ushort* Upan = (ushort*)(ws + 16);   // 512 bf16 (1 KiB)
    ushort* Wtg  = (ushort*)(ws + 272);  // 8192 bf16, byte off 1088 (16B-aligned)

    const int N = in_sizes[0] / DDIM;
    const int ntiles = N >> 4;

    gmm_prep<<<KMIX, 512, 0, stream>>>(sig, mus, phis, Wtg, Upan, pa2, pc);

    // A: identical to round 8 (keeps T8 comparability)
    const int gridA = (ntiles + 4 * 5 - 1) / (4 * 5);
    gmm_main<5><<<gridA, 256, 0, stream>>>(X, Wtg, Upan, pa2, pc, out, N);

    // B: TPW=10 clone, idempotent re-write of the same output.
    // Its solo duration = T9 - T8 (stream-order serialized after A).
    const int gridB = (ntiles + 4 * 10 - 1) / (4 * 10);
    gmm_main<10><<<gridB, 256, 0, stream>>>(X, Wtg, Upan, pa2, pc, out, N);
}

// Round 10
// 90.418 us; speedup vs baseline: 1.0443x; 1.0443x over previous
//
#include <hip/hip_runtime.h>
#include <hip/hip_bf16.h>
#include <math.h>

#define DDIM 32
#define KMIX 8
#define TPW 10  // 16-row tiles per wave

typedef short bf16x8 __attribute__((ext_vector_type(8)));
typedef float f32x4 __attribute__((ext_vector_type(4)));

__device__ __forceinline__ ushort to_bf16_rne(float f) {
    unsigned u = __builtin_bit_cast(unsigned, f);
    u = (u + 0x7FFFu + ((u >> 16) & 1u)) >> 16;
    return (ushort)u;
}

// ---------- prep: compact LU (SPD, no pivot) -> Newton tri-inverse -> panels.
// Sigma = Lg D Lg^T  (Doolittle LU: multipliers below diag, pivots on diag).
// V = Lg^{-1} via Newton V<-2V-V(NV): E_{k+1}=E_k^2, E_0 strictly lower ->
// EXACT after 5 iterations. L_target = Lg^{-T} D^{-1/2}  (UPPER triangular).
// Outputs: Wtg (bf16 frag-order panel of L_target), wvec[k][e] = (L^T mu)_e,
// pa2 = -0.5*phi*log2e, pc = -phi*exp(log_den)*log2e.
__global__ __launch_bounds__(256) void gmm_prep(
    const float* __restrict__ S, const float* __restrict__ mus,
    const float* __restrict__ phis, ushort* __restrict__ Wtg,
    float* __restrict__ wvec, float* __restrict__ pa2, float* __restrict__ pc)
{
    __shared__ float A[DDIM][DDIM + 1];
    __shared__ float V0[DDIM][DDIM + 1];
    __shared__ float V1[DDIM][DDIM + 1];
    __shared__ float T[DDIM][DDIM + 1];
    __shared__ float pivd[DDIM], irt[DDIM], muL[DDIM];
    const int k = blockIdx.x;
    const int t = threadIdx.x;   // 0..255
    const int r = t >> 3;        // 0..31
    const int c0 = t & 7;        // cols c0, c0+8, c0+16, c0+24

#pragma unroll
    for (int i = 0; i < 4; ++i) {
        const int c = c0 + 8 * i;
        A[r][c]  = S[k * 1024 + r * 32 + c];
        V0[r][c] = (r == c) ? 1.f : 0.f;
        V1[r][c] = 0.f;
    }
    if (t < DDIM) muL[t] = mus[k * 32 + t];
    __syncthreads();

    // compact LU, 32 phases (2-barrier pre-read pattern, validated shape)
    for (int p = 0; p < DDIM; ++p) {
        const float piv = A[p][p];
        const float fr  = A[r][p];
        float prow[4];
#pragma unroll
        for (int i = 0; i < 4; ++i) prow[i] = A[p][c0 + 8 * i];
        __syncthreads();
        const float fi = fr * __builtin_amdgcn_rcpf(piv);
        if (r > p) {
#pragma unroll
            for (int i = 0; i < 4; ++i) {
                const int c = c0 + 8 * i;
                if (c > p)       A[r][c] = fmaf(-fi, prow[i], A[r][c]);
                else if (c == p) A[r][c] = fi;  // store multiplier
            }
        }
        if (t == (p << 3)) pivd[p] = piv;
        __syncthreads();
    }

    // Newton inverse of unit-lower Lg (N = I + strict-lower(A)); 5 iters exact.
    auto newton = [&](float (*Vc)[DDIM + 1], float (*Vn)[DDIM + 1]) {
#pragma unroll
        for (int i = 0; i < 4; ++i) {
            const int c = c0 + 8 * i;
            if (c <= r) {
                float s = Vc[r][c];                       // N diag (=1) term
                for (int j = c; j < r; ++j) s = fmaf(A[r][j], Vc[j][c], s);
                T[r][c] = s;                              // (N*Vc)[r][c]
            }
        }
        __syncthreads();
#pragma unroll
        for (int i = 0; i < 4; ++i) {
            const int c = c0 + 8 * i;
            if (c <= r) {
                float s = 0.f;
                for (int j = c; j <= r; ++j) s = fmaf(Vc[r][j], T[j][c], s);
                Vn[r][c] = fmaf(2.f, Vc[r][c], -s);       // 2V - V(NV)
            }
        }
        __syncthreads();
    };
    newton(V0, V1); newton(V1, V0); newton(V0, V1); newton(V1, V0); newton(V0, V1);
    // final V = V1 = Lg^{-1}

    if (t < DDIM) {
        irt[t] = rsqrtf(pivd[t]);
        float z = 0.f;                                    // z = V*mu (row t)
        for (int j = 0; j <= t; ++j) z = fmaf(V1[t][j], muL[j], z);
        wvec[k * 32 + t] = z * rsqrtf(pivd[t]);           // w = D^{-1/2} V mu
    }
    __syncthreads();

    // pack L_target[d][e] = V1[e][d]*irt[e]  (upper-tri), frag order:
    // Wtg[k*1024 + h*512 + lane*8 + j] = L[d=(lane>>4)*8+j][e=h*16+(lane&15)]
#pragma unroll
    for (int rep = 0; rep < 4; ++rep) {
        const int i = t + 256 * rep;
        const int h = i >> 9, lane = (i >> 3) & 63, j = i & 7;
        const int d = (lane >> 4) * 8 + j;
        const int e = h * 16 + (lane & 15);
        const float fv = (e >= d) ? V1[e][d] * irt[e] : 0.f;
        Wtg[k * 1024 + i] = to_bf16_rne(fv);
    }

    if (t < 64) {  // logdet = sum log pivd, wave-0 butterfly
        float l = (t < DDIM) ? logf(pivd[t]) : 0.f;
        for (int off = 32; off; off >>= 1) l += __shfl_xor(l, off, 64);
        if (t == 0) {
            const float eld = expf(0.5f * (DDIM * 1.8378770664093453f + l));
            const float LOG2E = 1.4426950408889634f;
            pa2[k] = -0.5f * phis[k] * LOG2E;
            pc[k]  = -phis[k] * eld * LOG2E;
        }
    }
}

// ---------- DPP helpers -----------------------------------------------------
template <int CTRL>
__device__ __forceinline__ float dpp_add(float v) {
    int t = __builtin_amdgcn_update_dpp(0, __builtin_bit_cast(int, v), CTRL, 0xF, 0xF, true);
    return v + __builtin_bit_cast(float, t);
}
__device__ __forceinline__ float sel4(float a0, float a1, float a2, float a3, int r) {
    float b0 = (r & 1) ? a1 : a0;
    float b1 = (r & 1) ? a3 : a2;
    return (r & 2) ? b1 : b0;
}

// ---------- main: q = ||L^T x - w||^2 via MFMA self-dot, w folded pre-square.
// Lane (g = lane>>4, c = lane&15) finalizes row r1 = g*4+(c&3), k-pair p = c>>2.
// Upper-tri L: wf0 (cols e<16) is zero for lanes >=32 -> exec-masked read.
__global__ __launch_bounds__(256, 6) void gmm_main(
    const float* __restrict__ X, const ushort* __restrict__ Wtg,
    const float* __restrict__ wvec, const float* __restrict__ pa2g,
    const float* __restrict__ pcg, float* __restrict__ out, int N)
{
    __shared__ ushort wtab[KMIX * 1024];  // 16 KiB: [k][h][lane][8 bf16]
    const int tid = threadIdx.x;
    const int lane = tid & 63;
    const int wid = tid >> 6;
    const int g = lane >> 4;
    const int c = lane & 15;
    const int rsel = c & 3;
    const int r1 = g * 4 + rsel;
    const int p = c >> 2;

    {
        const float4* src = (const float4*)Wtg;
        float4* dst = (float4*)wtab;
#pragma unroll
        for (int i = 0; i < 4; ++i) dst[tid + 256 * i] = src[tid + 256 * i];
    }

    // negative w constants: nw0[k] = -w[k][c], nw1[k] = -w[k][c+16]
    float nw0[KMIX], nw1[KMIX];
#pragma unroll
    for (int k = 0; k < KMIX; ++k) {
        nw0[k] = -wvec[k * 32 + c];
        nw1[k] = -wvec[k * 32 + 16 + c];
    }
    float pcv0 = pcg[0], pcv1 = pcg[1], pcv2 = pcg[2], pcv3 = pcg[3];
    float pcv4 = pcg[4], pcv5 = pcg[5], pcv6 = pcg[6], pcv7 = pcg[7];
    const float m8 = fmaxf(fmaxf(fmaxf(pcv0, pcv1), fmaxf(pcv2, pcv3)),
                           fmaxf(fmaxf(pcv4, pcv5), fmaxf(pcv6, pcv7)));
    const float paA = pa2g[2 * p], paB = pa2g[2 * p + 1];
    const float pcsA = pcg[2 * p] - m8, pcsB = pcg[2 * p + 1] - m8;

    const int ntiles = N >> 4;
    const int tile0 = (blockIdx.x * 4 + wid) * TPW;
    const float* lp = X + (size_t)tile0 * 512 + c * 32 + g * 8;
    float* op = out + (size_t)(tile0 * 16 + r1) * 8 + p * 2;

    const f32x4 zro = {0.f, 0.f, 0.f, 0.f};
    float4 a0 = {0,0,0,0}, a1 = {0,0,0,0};
    if (tile0 < ntiles) { a0 = *(const float4*)lp; a1 = *(const float4*)(lp + 4); }

    __syncthreads();  // wtab ready

#pragma unroll
    for (int it = 0; it < TPW; ++it) {
        const int tile = tile0 + it;
        float4 b0 = a0, b1 = a1;
        if (it + 1 < TPW && tile + 1 < ntiles) {
            b0 = *(const float4*)(lp + 512);
            b1 = *(const float4*)(lp + 516);
        }
        if (tile < ntiles) {
            int4 xi;
            xi.x = __builtin_amdgcn_perm(__builtin_bit_cast(unsigned, a0.y), __builtin_bit_cast(unsigned, a0.x), 0x07060302u);
            xi.y = __builtin_amdgcn_perm(__builtin_bit_cast(unsigned, a0.w), __builtin_bit_cast(unsigned, a0.z), 0x07060302u);
            xi.z = __builtin_amdgcn_perm(__builtin_bit_cast(unsigned, a1.y), __builtin_bit_cast(unsigned, a1.x), 0x07060302u);
            xi.w = __builtin_amdgcn_perm(__builtin_bit_cast(unsigned, a1.w), __builtin_bit_cast(unsigned, a1.z), 0x07060302u);
            const bf16x8 xf = __builtin_bit_cast(bf16x8, xi);

            int la = lane * 16;
            asm volatile("" : "+v"(la));  // defeat LICM on frag reads
            const char* wb = (const char*)wtab + la;

            float qa = 0.f, qb = 0.f;
#pragma unroll
            for (int k = 0; k < KMIX; ++k) {
                bf16x8 wf0k = {0, 0, 0, 0, 0, 0, 0, 0};
                if (lane < 32)  // upper-tri: cols e<16 zero for rows d>=16
                    wf0k = *(const bf16x8*)(wb + (k * 2 + 0) * 1024);
                const bf16x8 wf1k = *(const bf16x8*)(wb + (k * 2 + 1) * 1024);
                f32x4 acc0 = __builtin_amdgcn_mfma_f32_16x16x32_bf16(xf, wf0k, zro, 0, 0, 0);
                f32x4 acc1 = __builtin_amdgcn_mfma_f32_16x16x32_bf16(xf, wf1k, zro, 0, 0, 0);
                const float d00 = acc0[0] + nw0[k], d10 = acc1[0] + nw1[k];
                const float d01 = acc0[1] + nw0[k], d11 = acc1[1] + nw1[k];
                const float d02 = acc0[2] + nw0[k], d12 = acc1[2] + nw1[k];
                const float d03 = acc0[3] + nw0[k], d13 = acc1[3] + nw1[k];
                float p0 = fmaf(d10, d10, d00 * d00);
                float p1 = fmaf(d11, d11, d01 * d01);
                float p2 = fmaf(d12, d12, d02 * d02);
                float p3 = fmaf(d13, d13, d03 * d03);
                p0 = dpp_add<0xB1>(p0); p0 = dpp_add<0x4E>(p0);
                p1 = dpp_add<0xB1>(p1); p1 = dpp_add<0x4E>(p1);
                p2 = dpp_add<0xB1>(p2); p2 = dpp_add<0x4E>(p2);
                p3 = dpp_add<0xB1>(p3); p3 = dpp_add<0x4E>(p3);
                float v = sel4(p0, p1, p2, p3, rsel);   // keep row g*4+(c&3)
                v = dpp_add<0x124>(v);                  // row_ror:4
                v = dpp_add<0x128>(v);                  // row_ror:8
                if ((k >> 1) == 0) { if (p == 0) { if (k & 1) qb = v; else qa = v; } }
                if ((k >> 1) == 1) { if (p == 1) { if (k & 1) qb = v; else qa = v; } }
                if ((k >> 1) == 2) { if (p == 2) { if (k & 1) qb = v; else qa = v; } }
                if ((k >> 1) == 3) { if (p == 3) { if (k & 1) qb = v; else qa = v; } }
            }

            const float aka = fmaf(paA, qa, pcsA);
            const float akb = fmaf(paB, qb, pcsB);
            const float ea = __builtin_amdgcn_exp2f(aka);
            const float eb = __builtin_amdgcn_exp2f(akb);
            float s = ea + eb;
            s = dpp_add<0x124>(s); s = dpp_add<0x128>(s);
            const float inv = __builtin_amdgcn_rcpf(s);
            *(float2*)op = make_float2(ea * inv, eb * inv);
        }
        a0 = b0; a1 = b1;
        lp += 512;
        op += 128;
    }
}

extern "C" void kernel_launch(void* const* d_in, const int* in_sizes, int n_in,
                              void* d_out, int out_size, void* d_ws, size_t ws_size,
                              hipStream_t stream) {
    const float* X    = (const float*)d_in[0];
    const float* mus  = (const float*)d_in[1];
    const float* sig  = (const float*)d_in[2];
    const float* phis = (const float*)d_in[3];
    float* out = (float*)d_out;

    float* ws    = (float*)d_ws;
    float* pa2   = ws;                   // 8 f32
    float* pc    = ws + 8;               // 8 f32
    float* wvec  = ws + 16;              // 256 f32
    ushort* Wtg  = (ushort*)(ws + 272);  // 8192 bf16, byte off 1088 (16B-aligned)

    const int N = in_sizes[0] / DDIM;
    const int ntiles = N >> 4;

    gmm_prep<<<KMIX, 256, 0, stream>>>(sig, mus, phis, Wtg, wvec, pa2, pc);

    const int grid = (ntiles + 4 * TPW - 1) / (4 * TPW);
    gmm_main<<<grid, 256, 0, stream>>>(X, Wtg, wvec, pa2, pc, out, N);
}

// Round 11
// 68.564 us; speedup vs baseline: 1.3772x; 1.3187x over previous
//
#include <hip/hip_runtime.h>
#include <hip/hip_bf16.h>
#include <math.h>

#define DDIM 32
#define KMIX 8
#define TPW 10  // 16-row tiles per wave

typedef short bf16x8 __attribute__((ext_vector_type(8)));
typedef float f32x4 __attribute__((ext_vector_type(4)));

__device__ __forceinline__ ushort to_bf16_rne(float f) {
    unsigned u = __builtin_bit_cast(unsigned, f);
    u = (u + 0x7FFFu + ((u >> 16) & 1u)) >> 16;
    return (ushort)u;
}

// ---------- prep: GJ inverse (SPD, no pivoting) -> Cholesky(Sigma^-1) -> panels.
// Round-8 validated structure (512 thr, 2-barrier O(1)-per-thread phases).
// Outputs: Wtg  = frag-order bf16 panel of L (lower-tri, chol of Sigma^-1)
//          wvec[k][e] = (L^T mu)[e]
//          pa2 = -0.5*phi*log2e,  pc = -phi*exp(log_den)*log2e
__global__ __launch_bounds__(512) void gmm_prep(
    const float* __restrict__ S, const float* __restrict__ mus,
    const float* __restrict__ phis, ushort* __restrict__ Wtg,
    float* __restrict__ wvec, float* __restrict__ pa2, float* __restrict__ pc)
{
    __shared__ float aug[DDIM][2 * DDIM + 2];  // stride 66
    __shared__ float ch[DDIM][DDIM + 1];       // stride 33
    __shared__ float pivsave[DDIM];
    __shared__ float wv[DDIM];
    const int k = blockIdx.x;
    const int t = threadIdx.x;   // 0..511
    const int r = t >> 4;        // 0..31
    const int c4 = t & 15;       // 0..15

    aug[r][c4]      = S[k * 1024 + r * 32 + c4];
    aug[r][c4 + 16] = S[k * 1024 + r * 32 + c4 + 16];
    aug[r][c4 + 32] = (c4 == r) ? 1.f : 0.f;
    aug[r][c4 + 48] = (c4 + 16 == r) ? 1.f : 0.f;
    __syncthreads();

    for (int p = 0; p < DDIM; ++p) {
        const float piv = aug[p][p];
        const float f   = aug[r][p];
        const float pr0 = aug[p][c4];
        const float pr1 = aug[p][c4 + 16];
        const float pr2 = aug[p][c4 + 32];
        const float pr3 = aug[p][c4 + 48];
        __syncthreads();
        const float ip = 1.f / piv;
        if (r == p) {
            aug[r][c4]      = pr0 * ip;
            aug[r][c4 + 16] = pr1 * ip;
            aug[r][c4 + 32] = pr2 * ip;
            aug[r][c4 + 48] = pr3 * ip;
            if (c4 == 0) pivsave[p] = piv;
        } else {
            const float fi = f * ip;
            aug[r][c4]      = fmaf(-fi, pr0, aug[r][c4]);
            aug[r][c4 + 16] = fmaf(-fi, pr1, aug[r][c4 + 16]);
            aug[r][c4 + 32] = fmaf(-fi, pr2, aug[r][c4 + 32]);
            aug[r][c4 + 48] = fmaf(-fi, pr3, aug[r][c4 + 48]);
        }
        __syncthreads();
    }

    ch[r][c4]      = aug[r][32 + c4];
    ch[r][c4 + 16] = aug[r][48 + c4];
    __syncthreads();

    // Cholesky (lower) of Ainv: 2-barrier pre-read pattern, 2 cells/thread.
    for (int j = 0; j < DDIM; ++j) {
        const float djj = ch[j][j];
        const float cr  = ch[r][j];
        const float cc0 = ch[c4][j];
        const float cc1 = ch[c4 + 16][j];
        __syncthreads();
        const float irs = rsqrtf(djj);
        const float ird = __builtin_amdgcn_rcpf(djj);
        if (c4 == j)                       ch[r][c4]      = (r >= j) ? cr * irs : 0.f;
        else if (r > j && c4 > j)          ch[r][c4]      = fmaf(-cr * ird, cc0, ch[r][c4]);
        if (c4 + 16 == j)                  ch[r][c4 + 16] = (r >= j) ? cr * irs : 0.f;
        else if (r > j && c4 + 16 > j)     ch[r][c4 + 16] = fmaf(-cr * ird, cc1, ch[r][c4 + 16]);
        __syncthreads();
    }

    // wvec[e] = sum_d L[d][e] * mu[d]  (column dot; banks distinct per lane)
    if (t < DDIM) {
        float acc = 0.f;
        for (int d = t; d < DDIM; ++d)         // L[d][e]=0 for d<e
            acc = fmaf(ch[d][t], mus[k * 32 + d], acc);
        wv[t] = acc;
        wvec[k * 32 + t] = acc;
    }
    __syncthreads();

    // fragment-order Wtg: thread writes h=0 (idx t) and h=1 (idx 512+t)
    {
        const int lane0 = (t >> 3) & 63, j0 = t & 7;
        const int d0 = (lane0 >> 4) * 8 + j0;
        const int e0 = lane0 & 15;
        const int e1 = 16 + e0;
        const float f0 = (d0 >= e0) ? ch[d0][e0] : 0.f;
        const float f1 = (d0 >= e1) ? ch[d0][e1] : 0.f;
        Wtg[k * 1024 + t]       = to_bf16_rne(f0);
        Wtg[k * 1024 + 512 + t] = to_bf16_rne(f1);
    }
    if (t == 0) {
        float ldet = 0.f;
        for (int i = 0; i < DDIM; ++i) ldet += logf(fabsf(pivsave[i]));
        const float eld = expf(0.5f * (DDIM * 1.8378770664093453f + ldet));
        const float LOG2E = 1.4426950408889634f;
        pa2[k] = -0.5f * phis[k] * LOG2E;
        pc[k]  = -phis[k] * eld * LOG2E;
    }
}

// ---------- DPP helpers -----------------------------------------------------
template <int CTRL>
__device__ __forceinline__ float dpp_add(float v) {
    int t = __builtin_amdgcn_update_dpp(0, __builtin_bit_cast(int, v), CTRL, 0xF, 0xF, true);
    return v + __builtin_bit_cast(float, t);
}
__device__ __forceinline__ float sel4(float a0, float a1, float a2, float a3, int r) {
    float b0 = (r & 1) ? a1 : a0;
    float b1 = (r & 1) ? a3 : a2;
    return (r & 2) ? b1 : b0;
}

// ---------- main: q = ||L^T x - w||^2 via MFMA self-dot, w folded pre-square.
// Lane (g = lane>>4, c = lane&15) finalizes row r1 = g*4+(c&3), k-pair p = c>>2.
// Lower-tri L: wf1 (cols e>=16) zero for rows d<16 -> exec-masked read (lane>=32).
__global__ __launch_bounds__(256, 6) void gmm_main(
    const float* __restrict__ X, const ushort* __restrict__ Wtg,
    const float* __restrict__ wvec, const float* __restrict__ pa2g,
    const float* __restrict__ pcg, float* __restrict__ out, int N)
{
    __shared__ ushort wtab[KMIX * 1024];  // 16 KiB: [k][h][lane][8 bf16]
    const int tid = threadIdx.x;
    const int lane = tid & 63;
    const int wid = tid >> 6;
    const int g = lane >> 4;
    const int c = lane & 15;
    const int rsel = c & 3;
    const int r1 = g * 4 + rsel;
    const int p = c >> 2;

    {
        const float4* src = (const float4*)Wtg;
        float4* dst = (float4*)wtab;
#pragma unroll
        for (int i = 0; i < 4; ++i) dst[tid + 256 * i] = src[tid + 256 * i];
    }

    // negative w constants: nw0[k] = -w[k][c], nw1[k] = -w[k][c+16]
    float nw0[KMIX], nw1[KMIX];
#pragma unroll
    for (int k = 0; k < KMIX; ++k) {
        nw0[k] = -wvec[k * 32 + c];
        nw1[k] = -wvec[k * 32 + 16 + c];
    }
    float pcv0 = pcg[0], pcv1 = pcg[1], pcv2 = pcg[2], pcv3 = pcg[3];
    float pcv4 = pcg[4], pcv5 = pcg[5], pcv6 = pcg[6], pcv7 = pcg[7];
    const float m8 = fmaxf(fmaxf(fmaxf(pcv0, pcv1), fmaxf(pcv2, pcv3)),
                           fmaxf(fmaxf(pcv4, pcv5), fmaxf(pcv6, pcv7)));
    const float paA = pa2g[2 * p], paB = pa2g[2 * p + 1];
    const float pcsA = pcg[2 * p] - m8, pcsB = pcg[2 * p + 1] - m8;

    const int ntiles = N >> 4;
    const int tile0 = (blockIdx.x * 4 + wid) * TPW;
    const float* lp = X + (size_t)tile0 * 512 + c * 32 + g * 8;
    float* op = out + (size_t)(tile0 * 16 + r1) * 8 + p * 2;

    const f32x4 zro = {0.f, 0.f, 0.f, 0.f};
    float4 a0 = {0,0,0,0}, a1 = {0,0,0,0};
    if (tile0 < ntiles) { a0 = *(const float4*)lp; a1 = *(const float4*)(lp + 4); }

    __syncthreads();  // wtab ready

#pragma unroll
    for (int it = 0; it < TPW; ++it) {
        const int tile = tile0 + it;
        float4 b0 = a0, b1 = a1;
        if (it + 1 < TPW && tile + 1 < ntiles) {
            b0 = *(const float4*)(lp + 512);
            b1 = *(const float4*)(lp + 516);
        }
        if (tile < ntiles) {
            int4 xi;
            xi.x = __builtin_amdgcn_perm(__builtin_bit_cast(unsigned, a0.y), __builtin_bit_cast(unsigned, a0.x), 0x07060302u);
            xi.y = __builtin_amdgcn_perm(__builtin_bit_cast(unsigned, a0.w), __builtin_bit_cast(unsigned, a0.z), 0x07060302u);
            xi.z = __builtin_amdgcn_perm(__builtin_bit_cast(unsigned, a1.y), __builtin_bit_cast(unsigned, a1.x), 0x07060302u);
            xi.w = __builtin_amdgcn_perm(__builtin_bit_cast(unsigned, a1.w), __builtin_bit_cast(unsigned, a1.z), 0x07060302u);
            const bf16x8 xf = __builtin_bit_cast(bf16x8, xi);

            int la = lane * 16;
            asm volatile("" : "+v"(la));  // defeat LICM on frag reads
            const char* wb = (const char*)wtab + la;

            float qa = 0.f, qb = 0.f;
#pragma unroll
            for (int k = 0; k < KMIX; ++k) {
                const bf16x8 wf0k = *(const bf16x8*)(wb + (k * 2 + 0) * 1024);
                bf16x8 wf1k = {0, 0, 0, 0, 0, 0, 0, 0};
                if (lane >= 32)  // lower-tri: cols e>=16 zero for rows d<16
                    wf1k = *(const bf16x8*)(wb + (k * 2 + 1) * 1024);
                f32x4 acc0 = __builtin_amdgcn_mfma_f32_16x16x32_bf16(xf, wf0k, zro, 0, 0, 0);
                f32x4 acc1 = __builtin_amdgcn_mfma_f32_16x16x32_bf16(xf, wf1k, zro, 0, 0, 0);
                const float d00 = acc0[0] + nw0[k], d10 = acc1[0] + nw1[k];
                const float d01 = acc0[1] + nw0[k], d11 = acc1[1] + nw1[k];
                const float d02 = acc0[2] + nw0[k], d12 = acc1[2] + nw1[k];
                const float d03 = acc0[3] + nw0[k], d13 = acc1[3] + nw1[k];
                float p0 = fmaf(d10, d10, d00 * d00);
                float p1 = fmaf(d11, d11, d01 * d01);
                float p2 = fmaf(d12, d12, d02 * d02);
                float p3 = fmaf(d13, d13, d03 * d03);
                p0 = dpp_add<0xB1>(p0); p0 = dpp_add<0x4E>(p0);
                p1 = dpp_add<0xB1>(p1); p1 = dpp_add<0x4E>(p1);
                p2 = dpp_add<0xB1>(p2); p2 = dpp_add<0x4E>(p2);
                p3 = dpp_add<0xB1>(p3); p3 = dpp_add<0x4E>(p3);
                float v = sel4(p0, p1, p2, p3, rsel);   // keep row g*4+(c&3)
                v = dpp_add<0x124>(v);                  // row_ror:4
                v = dpp_add<0x128>(v);                  // row_ror:8
                if ((k >> 1) == 0) { if (p == 0) { if (k & 1) qb = v; else qa = v; } }
                if ((k >> 1) == 1) { if (p == 1) { if (k & 1) qb = v; else qa = v; } }
                if ((k >> 1) == 2) { if (p == 2) { if (k & 1) qb = v; else qa = v; } }
                if ((k >> 1) == 3) { if (p == 3) { if (k & 1) qb = v; else qa = v; } }
            }

            const float aka = fmaf(paA, qa, pcsA);
            const float akb = fmaf(paB, qb, pcsB);
            const float ea = __builtin_amdgcn_exp2f(aka);
            const float eb = __builtin_amdgcn_exp2f(akb);
            float s = ea + eb;
            s = dpp_add<0x124>(s); s = dpp_add<0x128>(s);
            const float inv = __builtin_amdgcn_rcpf(s);
            *(float2*)op = make_float2(ea * inv, eb * inv);
        }
        a0 = b0; a1 = b1;
        lp += 512;
        op += 128;
    }
}

extern "C" void kernel_launch(void* const* d_in, const int* in_sizes, int n_in,
                              void* d_out, int out_size, void* d_ws, size_t ws_size,
                              hipStream_t stream) {
    const float* X    = (const float*)d_in[0];
    const float* mus  = (const float*)d_in[1];
    const float* sig  = (const float*)d_in[2];
    const float* phis = (const float*)d_in[3];
    float* out = (float*)d_out;

    float* ws    = (float*)d_ws;
    float* pa2   = ws;                   // 8 f32
    float* pc    = ws + 8;               // 8 f32
    float* wvec  = ws + 16;              // 256 f32
    ushort* Wtg  = (ushort*)(ws + 272);  // 8192 bf16, byte off 1088 (16B-aligned)

    const int N = in_sizes[0] / DDIM;
    const int ntiles = N >> 4;

    gmm_prep<<<KMIX, 512, 0, stream>>>(sig, mus, phis, Wtg, wvec, pa2, pc);

    const int grid = (ntiles + 4 * TPW - 1) / (4 * TPW);
    gmm_main<<<grid, 256, 0, stream>>>(X, Wtg, wvec, pa2, pc, out, N);
}

// Round 12
// 53.385 us; speedup vs baseline: 1.7687x; 1.2843x over previous
//
#include <hip/hip_runtime.h>
#include <hip/hip_bf16.h>
#include <math.h>

#define DDIM 32
#define KMIX 8
#define TPW 10  // 16-row tiles per wave

typedef short bf16x8 __attribute__((ext_vector_type(8)));
typedef float f32x4 __attribute__((ext_vector_type(4)));

__device__ __forceinline__ ushort to_bf16_rne(float f) {
    unsigned u = __builtin_bit_cast(unsigned, f);
    u = (u + 0x7FFFu + ((u >> 16) & 1u)) >> 16;
    return (ushort)u;
}

// ---------- prep: FORWARD elimination only: [Sigma | I] -> [U | Lg^{-1}],
// Sigma = Lg D Lg^T (SPD, no pivoting). Self-dot factor L = Lg^{-T} D^{-1/2}
// (upper-tri): L[d][e] = Lg^{-1}[e][d] * rsqrt(U[e][e]).
// 32 phases (half of GJ+chol), 512 threads, validated 2-barrier pattern.
// Outputs: Wtg (frag-order bf16 panel of L), Upan[kk][d] = phi*log2e*amu[d]
// (rows 8..15 zero), pa2 = -0.5*phi*log2e, pc = (-0.5*phi*|w|^2 - phi*eld)*log2e.
__global__ __launch_bounds__(512) void gmm_prep(
    const float* __restrict__ S, const float* __restrict__ mus,
    const float* __restrict__ phis, ushort* __restrict__ Wtg,
    ushort* __restrict__ Upan, float* __restrict__ pa2, float* __restrict__ pc)
{
    __shared__ float aug[DDIM][2 * DDIM + 2];  // stride 66
    __shared__ float pivsave[DDIM];
    __shared__ float irts[DDIM];
    __shared__ float wv[DDIM];
    const int k = blockIdx.x;
    const int t = threadIdx.x;   // 0..511
    const int r = t >> 4;        // 0..31
    const int c4 = t & 15;       // 0..15

    aug[r][c4]      = S[k * 1024 + r * 32 + c4];
    aug[r][c4 + 16] = S[k * 1024 + r * 32 + c4 + 16];
    aug[r][c4 + 32] = (c4 == r) ? 1.f : 0.f;
    aug[r][c4 + 48] = (c4 + 16 == r) ? 1.f : 0.f;
    __syncthreads();

    // forward elimination (rows r > p only; row p untouched -> U row)
    for (int p = 0; p < DDIM; ++p) {
        const float piv = aug[p][p];
        const float f   = aug[r][p];
        const float pr0 = aug[p][c4];
        const float pr1 = aug[p][c4 + 16];
        const float pr2 = aug[p][c4 + 32];
        const float pr3 = aug[p][c4 + 48];
        __syncthreads();
        if (r > p) {
            const float fi = f * __builtin_amdgcn_rcpf(piv);
            aug[r][c4]      = fmaf(-fi, pr0, aug[r][c4]);
            aug[r][c4 + 16] = fmaf(-fi, pr1, aug[r][c4 + 16]);
            aug[r][c4 + 32] = fmaf(-fi, pr2, aug[r][c4 + 32]);
            aug[r][c4 + 48] = fmaf(-fi, pr3, aug[r][c4 + 48]);
        }
        if (t == (p << 4)) pivsave[p] = piv;
        __syncthreads();
    }

    if (t < DDIM) irts[t] = rsqrtf(pivsave[t]);
    __syncthreads();

    // wv[e] = (L^T mu)[e] = irt[e] * sum_{d<=e} Lg^{-1}[e][d] * mu[d]
    if (t < DDIM) {
        float acc = 0.f;
        for (int d = 0; d <= t; ++d)
            acc = fmaf(aug[t][32 + d], mus[k * 32 + d], acc);
        wv[t] = acc * irts[t];
    }
    __syncthreads();

    // amu[d] = (Sigma^-1 mu)[d] = sum_{e>=d} L[d][e] * wv[e]
    if (t < DDIM) {
        float acc = 0.f;
        for (int e = t; e < DDIM; ++e)
            acc = fmaf(aug[e][32 + t] * irts[e], wv[e], acc);
        Upan[k * 32 + t] = to_bf16_rne(phis[k] * 1.4426950408889634f * acc);
    }
    if (k == 0 && t >= 256) Upan[t] = 0;  // U-panel rows 8..15 = 0

    // frag-order pack: Wtg[k*1024 + h*512 + lane*8 + j] = L[d][e],
    // d = (lane>>4)*8 + j, e = h*16 + (lane&15); L upper-tri (d<=e).
    {
        const int lane0 = (t >> 3) & 63, j0 = t & 7;
        const int d0 = (lane0 >> 4) * 8 + j0;
        const int e0 = lane0 & 15;
        const int e1 = 16 + e0;
        const float f0 = (d0 <= e0) ? aug[e0][32 + d0] * irts[e0] : 0.f;
        const float f1 = (d0 <= e1) ? aug[e1][32 + d0] * irts[e1] : 0.f;
        Wtg[k * 1024 + t]       = to_bf16_rne(f0);
        Wtg[k * 1024 + 512 + t] = to_bf16_rne(f1);
    }

    // logdet + |w|^2 via wave-0 butterflies
    if (t < 64) {
        float l  = (t < DDIM) ? logf(pivsave[t]) : 0.f;
        float w2 = (t < DDIM) ? wv[t] * wv[t] : 0.f;
        for (int off = 32; off; off >>= 1) {
            l  += __shfl_xor(l, off, 64);
            w2 += __shfl_xor(w2, off, 64);
        }
        if (t == 0) {
            const float eld = expf(0.5f * (DDIM * 1.8378770664093453f + l));
            const float LOG2E = 1.4426950408889634f;
            pa2[k] = -0.5f * phis[k] * LOG2E;
            pc[k]  = (-0.5f * phis[k] * w2 - phis[k] * eld) * LOG2E;
        }
    }
}

// ---------- DPP helpers -----------------------------------------------------
template <int CTRL>
__device__ __forceinline__ float dpp_add(float v) {
    int t = __builtin_amdgcn_update_dpp(0, __builtin_bit_cast(int, v), CTRL, 0xF, 0xF, true);
    return v + __builtin_bit_cast(float, t);
}
__device__ __forceinline__ float sel4(float a0, float a1, float a2, float a3, int r) {
    float b0 = (r & 1) ? a1 : a0;
    float b1 = (r & 1) ? a3 : a2;
    return (r & 2) ? b1 : b0;
}
__device__ __forceinline__ float bperm_f(int addr, float v) {
    return __builtin_bit_cast(float, __builtin_amdgcn_ds_bpermute(addr, __builtin_bit_cast(int, v)));
}

// ---------- main: round-9 mainB body (measured 37.2 us), upper-tri mask -----
// q = ||L^T x||^2 via MFMA self-dot; linear term via 1 MFMA + bperm.
// Lane (g = lane>>4, c = lane&15) finalizes row r1 = g*4+(c&3), k-pair p = c>>2.
// Upper-tri L: wf0 (cols e<16) zero for rows d>=16 -> read only lanes < 32.
__global__ __launch_bounds__(256, 6) void gmm_main(
    const float* __restrict__ X, const ushort* __restrict__ Wtg,
    const ushort* __restrict__ Upan, const float* __restrict__ pa2g,
    const float* __restrict__ pcg, float* __restrict__ out, int N)
{
    __shared__ ushort wtab[KMIX * 1024];  // 16 KiB: [k][h][lane][8 bf16]
    const int tid = threadIdx.x;
    const int lane = tid & 63;
    const int wid = tid >> 6;
    const int g = lane >> 4;
    const int c = lane & 15;
    const int rsel = c & 3;
    const int r1 = g * 4 + rsel;
    const int p = c >> 2;

    {
        const float4* src = (const float4*)Wtg;
        float4* dst = (float4*)wtab;
#pragma unroll
        for (int i = 0; i < 4; ++i) dst[tid + 256 * i] = src[tid + 256 * i];
    }

    const bf16x8 uf = *(const bf16x8*)(Upan + c * 32 + g * 8);  // A-frag of U
    float pcv0 = pcg[0], pcv1 = pcg[1], pcv2 = pcg[2], pcv3 = pcg[3];
    float pcv4 = pcg[4], pcv5 = pcg[5], pcv6 = pcg[6], pcv7 = pcg[7];
    const float m8 = fmaxf(fmaxf(fmaxf(pcv0, pcv1), fmaxf(pcv2, pcv3)),
                           fmaxf(fmaxf(pcv4, pcv5), fmaxf(pcv6, pcv7)));
    const float paA = pa2g[2 * p], paB = pa2g[2 * p + 1];
    const float pcsA = pcg[2 * p] - m8, pcsB = pcg[2 * p + 1] - m8;
    const int src_byte = (((p >> 1) * 16 + r1) << 2);

    const int ntiles = N >> 4;
    const int tile0 = (blockIdx.x * 4 + wid) * TPW;
    const float* lp = X + (size_t)tile0 * 512 + c * 32 + g * 8;
    float* op = out + (size_t)(tile0 * 16 + r1) * 8 + p * 2;

    const f32x4 zro = {0.f, 0.f, 0.f, 0.f};
    float4 a0 = {0,0,0,0}, a1 = {0,0,0,0};
    if (tile0 < ntiles) { a0 = *(const float4*)lp; a1 = *(const float4*)(lp + 4); }

    __syncthreads();  // wtab ready

#pragma unroll
    for (int it = 0; it < TPW; ++it) {
        const int tile = tile0 + it;
        float4 b0 = a0, b1 = a1;
        if (it + 1 < TPW && tile + 1 < ntiles) {
            b0 = *(const float4*)(lp + 512);
            b1 = *(const float4*)(lp + 516);
        }
        if (tile < ntiles) {
            int4 xi;
            xi.x = __builtin_amdgcn_perm(__builtin_bit_cast(unsigned, a0.y), __builtin_bit_cast(unsigned, a0.x), 0x07060302u);
            xi.y = __builtin_amdgcn_perm(__builtin_bit_cast(unsigned, a0.w), __builtin_bit_cast(unsigned, a0.z), 0x07060302u);
            xi.z = __builtin_amdgcn_perm(__builtin_bit_cast(unsigned, a1.y), __builtin_bit_cast(unsigned, a1.x), 0x07060302u);
            xi.w = __builtin_amdgcn_perm(__builtin_bit_cast(unsigned, a1.w), __builtin_bit_cast(unsigned, a1.z), 0x07060302u);
            const bf16x8 xf = __builtin_bit_cast(bf16x8, xi);

            const f32x4 lin = __builtin_amdgcn_mfma_f32_16x16x32_bf16(uf, xf, zro, 0, 0, 0);

            int la = lane * 16;
            asm volatile("" : "+v"(la));  // defeat LICM on frag reads
            const char* wb = (const char*)wtab + la;

            float qa = 0.f, qb = 0.f;
#pragma unroll
            for (int k = 0; k < KMIX; ++k) {
                bf16x8 wf0k = {0, 0, 0, 0, 0, 0, 0, 0};
                if (lane < 32)  // upper-tri: cols e<16 zero for rows d>=16
                    wf0k = *(const bf16x8*)(wb + (k * 2 + 0) * 1024);
                const bf16x8 wf1k = *(const bf16x8*)(wb + (k * 2 + 1) * 1024);
                f32x4 acc0 = __builtin_amdgcn_mfma_f32_16x16x32_bf16(xf, wf0k, zro, 0, 0, 0);
                f32x4 acc1 = __builtin_amdgcn_mfma_f32_16x16x32_bf16(xf, wf1k, zro, 0, 0, 0);
                float p0 = fmaf(acc1[0], acc1[0], acc0[0] * acc0[0]);
                float p1 = fmaf(acc1[1], acc1[1], acc0[1] * acc0[1]);
                float p2 = fmaf(acc1[2], acc1[2], acc0[2] * acc0[2]);
                float p3 = fmaf(acc1[3], acc1[3], acc0[3] * acc0[3]);
                p0 = dpp_add<0xB1>(p0); p0 = dpp_add<0x4E>(p0);
                p1 = dpp_add<0xB1>(p1); p1 = dpp_add<0x4E>(p1);
                p2 = dpp_add<0xB1>(p2); p2 = dpp_add<0x4E>(p2);
                p3 = dpp_add<0xB1>(p3); p3 = dpp_add<0x4E>(p3);
                float v = sel4(p0, p1, p2, p3, rsel);   // keep row g*4+(c&3)
                v = dpp_add<0x124>(v);                  // row_ror:4
                v = dpp_add<0x128>(v);                  // row_ror:8
                if ((k >> 1) == 0) { if (p == 0) { if (k & 1) qb = v; else qa = v; } }
                if ((k >> 1) == 1) { if (p == 1) { if (k & 1) qb = v; else qa = v; } }
                if ((k >> 1) == 2) { if (p == 2) { if (k & 1) qb = v; else qa = v; } }
                if ((k >> 1) == 3) { if (p == 3) { if (k & 1) qb = v; else qa = v; } }
            }

            const float l0 = bperm_f(src_byte, lin[0]);
            const float l1 = bperm_f(src_byte, lin[1]);
            const float l2 = bperm_f(src_byte, lin[2]);
            const float l3 = bperm_f(src_byte, lin[3]);
            const float lina = (p & 1) ? l2 : l0;
            const float linb = (p & 1) ? l3 : l1;
            const float aka = fmaf(paA, qa, pcsA) + lina;
            const float akb = fmaf(paB, qb, pcsB) + linb;

            const float ea = __builtin_amdgcn_exp2f(aka);
            const float eb = __builtin_amdgcn_exp2f(akb);
            float s = ea + eb;
            s = dpp_add<0x124>(s); s = dpp_add<0x128>(s);
            const float inv = __builtin_amdgcn_rcpf(s);
            *(float2*)op = make_float2(ea * inv, eb * inv);
        }
        a0 = b0; a1 = b1;
        lp += 512;
        op += 128;
    }
}

extern "C" void kernel_launch(void* const* d_in, const int* in_sizes, int n_in,
                              void* d_out, int out_size, void* d_ws, size_t ws_size,
                              hipStream_t stream) {
    const float* X    = (const float*)d_in[0];
    const float* mus  = (const float*)d_in[1];
    const float* sig  = (const float*)d_in[2];
    const float* phis = (const float*)d_in[3];
    float* out = (float*)d_out;

    float* ws    = (float*)d_ws;
    float* pa2   = ws;                   // 8 f32
    float* pc    = ws + 8;               // 8 f32
    ushort* Upan = (ushort*)(ws + 16);   // 512 bf16 (1 KiB)
    ushort* Wtg  = (ushort*)(ws + 272);  // 8192 bf16, byte off 1088 (16B-aligned)

    const int N = in_sizes[0] / DDIM;
    const int ntiles = N >> 4;

    gmm_prep<<<KMIX, 512, 0, stream>>>(sig, mus, phis, Wtg, Upan, pa2, pc);

    const int grid = (ntiles + 4 * TPW - 1) / (4 * TPW);
    gmm_main<<<grid, 256, 0, stream>>>(X, Wtg, Upan, pa2, pc, out, N);
}